// Round 14
// baseline (1707.087 us; speedup 1.0000x reference)
//
#include <hip/hip_runtime.h>

#define BB 16
#define TT 12
#define NN 1024
#define EMB 10
#define DIN 21
#define DOUT 64
#define FF 85      // DIN + DOUT
#define FP 96      // padded feature stride (gate spmv output cols)
#define KFP 176    // padded 2*FF (=170) for per-node matmul K dim (6 MFMA K-steps of 32)
#define C2P 24     // padded cur2 feature stride
#define BTN (BB * TT * NN)
#define ASCALE 256.0f
#define INV_ASCALE (1.0f / 256.0f)
#define LSCALE 4096.0f
#define INV_LSCALE (1.0f / 4096.0f)

typedef float4 f4;
typedef _Float16 f16;
typedef __attribute__((ext_vector_type(8))) _Float16 f16x8;
typedef __attribute__((ext_vector_type(4))) float f32x4;

// ---------------- cur hi/lo f16, BOTH layouts: [b][t][f][n] and [b][t][n][f(24)] ----------------
// Thread per (bt,n): computes all 21 features once; [f][n] stores stay coalesced (wave = n),
// [n][f] stores are 48B contiguous per thread. Bit-identical values in both layouts.
__global__ __launch_bounds__(256) void k_embedT(const float* __restrict__ x,
    const float* __restrict__ Wtod, const float* __restrict__ btod,
    const float* __restrict__ Wdow, const float* __restrict__ bdow,
    f16* __restrict__ curh, f16* __restrict__ curl,
    f16* __restrict__ cur2h, f16* __restrict__ cur2l) {
  int idx = blockIdx.x * 256 + threadIdx.x;
  if (idx >= BB * TT * NN) return;
  int n = idx & 1023;
  int bt = idx >> 10;
  const float* xp = x + ((size_t)bt * 1024 + n) * 3;
  float x0 = xp[0];
  int tod = (int)xp[1];
  int dow = (int)xp[2];
  f16 h2[C2P], l2[C2P];
#pragma unroll
  for (int f = 0; f < DIN; f++) {
    float v;
    if (f == 0) v = x0;
    else if (f < 1 + EMB) v = Wtod[tod * EMB + f - 1] + btod[f - 1];
    else v = Wdow[dow * EMB + f - 1 - EMB] + bdow[f - 1 - EMB];
    f16 hi = (f16)v;
    f16 lo = (f16)((v - (float)hi) * LSCALE);
    size_t ci = ((size_t)bt * DIN + f) * NN + n;
    curh[ci] = hi;
    curl[ci] = lo;
    h2[f] = hi;
    l2[f] = lo;
  }
#pragma unroll
  for (int f = DIN; f < C2P; f++) { h2[f] = (f16)0.f; l2[f] = (f16)0.f; }
  size_t b2 = ((size_t)bt * NN + n) * C2P;
#pragma unroll
  for (int q = 0; q < C2P / 8; q++) {
    *(f16x8*)(cur2h + b2 + q * 8) = *(f16x8*)&h2[q * 8];
    *(f16x8*)(cur2l + b2 + q * 8) = *(f16x8*)&l2[q * 8];
  }
}

// ---------------- Wpool transpose: [d][kf][o] -> Wp2[o][kc][d][j(8)], kf>=170 zeroed ----------------
__global__ __launch_bounds__(256) void k_wpT(const float* __restrict__ Wpool,
    float* __restrict__ Wp2, int O, int total) {
  int idx = blockIdx.x * 256 + threadIdx.x;
  if (idx >= total) return;
  int j = idx & 7;
  int d = (idx >> 3) % EMB;
  int kc = (idx / (8 * EMB)) % 22;
  int o = idx / (8 * EMB * 22);
  int kf = kc * 8 + j;
  Wp2[idx] = (kf < 2 * FF) ? Wpool[((size_t)d * 2 * FF + kf) * O + o] : 0.f;
}

// ---------------- pooled weights f16 hi/lo, MFMA layout W[n][o][k(176)] ----------------
__global__ __launch_bounds__(256) void k_poolT(const float* __restrict__ E,
    const float* __restrict__ Wp2, f16* __restrict__ Wh, f16* __restrict__ Wl,
    int O, int CH) {
  int n0 = blockIdx.y * 16;
  int c = blockIdx.x * 256 + threadIdx.x;
  __shared__ float Es[16][EMB];
  if (threadIdx.x < 16 * EMB)
    Es[threadIdx.x / EMB][threadIdx.x % EMB] =
        E[(n0 + threadIdx.x / EMB) * EMB + threadIdx.x % EMB];
  __syncthreads();
  if (c >= CH) return;
  const float* wb = Wp2 + (size_t)c * 80;
  float wv[80];
#pragma unroll
  for (int i = 0; i < 20; i++) *(f4*)&wv[i * 4] = *(const f4*)(wb + i * 4);
  for (int ni = 0; ni < 16; ni++) {
    f16x8 hv, lv;
#pragma unroll
    for (int j = 0; j < 8; j++) {
      float v = 0.f;
#pragma unroll
      for (int d = 0; d < EMB; d++) v = fmaf(Es[ni][d], wv[d * 8 + j], v);
      f16 hi = (f16)v;
      hv[j] = hi;
      lv[j] = (f16)((v - (float)hi) * LSCALE);
    }
    size_t base = ((size_t)(n0 + ni) * O * 22 + c) * 8;
    *(f16x8*)(Wh + base) = hv;
    *(f16x8*)(Wl + base) = lv;
  }
}

__global__ __launch_bounds__(256) void k_poolb(const float* __restrict__ E,
    const float* __restrict__ bpool, float* __restrict__ bvec, int O) {
  int idx = blockIdx.x * 256 + threadIdx.x;
  if (idx >= NN * O) return;
  int o = idx % O, n = idx / O;
  float a = 0.f;
#pragma unroll
  for (int d = 0; d < EMB; d++) a += E[n * EMB + d] * bpool[d * O + o];
  bvec[idx] = a;
}

// init h + transposed hi/lo h
__global__ __launch_bounds__(256) void k_inith(const float* __restrict__ s,
    float* __restrict__ hb, f16* __restrict__ hTh, f16* __restrict__ hTl) {
  int i = blockIdx.x * 256 + threadIdx.x;
  if (i >= BB * NN * DOUT) return;
  float v = s[i];
  hb[i] = v;
  int b = i >> 16;
  int n = (i >> 6) & 1023;
  int o = i & 63;
  f16 hi = (f16)v;
  size_t ti = (((size_t)(b * 64 + o)) << 10) + n;
  hTh[ti] = hi;
  hTl[ti] = (f16)((v - (float)hi) * LSCALE);
}

// ---------------- W_QKV -> wbt[3][d][k] f16 + biasb[192] ----------------
__global__ __launch_bounds__(256) void k_cvtw(const float* __restrict__ WQ,
    const float* __restrict__ WK, const float* __restrict__ WV,
    const float* __restrict__ bQ, const float* __restrict__ bK, const float* __restrict__ bV,
    f16* __restrict__ wbt, float* __restrict__ biasb) {
  int idx = blockIdx.x * 256 + threadIdx.x;
  if (idx < 3 * DOUT * DOUT) {
    int mat = idx >> 12;
    int d = (idx >> 6) & 63;
    int k = idx & 63;
    const float* W = mat == 0 ? WQ : (mat == 1 ? WK : WV);
    wbt[idx] = (f16)(W[k * DOUT + d]);
  } else if (idx < 3 * DOUT * DOUT + 192) {
    int j = idx - 3 * DOUT * DOUT;
    const float* bb = (j >> 6) == 0 ? bQ : ((j >> 6) == 1 ? bK : bV);
    biasb[j] = bb[j & 63];
  }
}

// ---------------- A = softmax(relu(scores))*256 -> Ah (plain f16) ----------------
// zfill=1 (t=0 only): also zero-fills T1g/T1c for the first step's atomics.
__global__ __launch_bounds__(256) void k_scores(const float* __restrict__ E,
    const float* __restrict__ ne1, const float* __restrict__ ne2, int t,
    f16* __restrict__ Ah,
    float* __restrict__ T1g, float* __restrict__ T1c, int zfill) {
  int b = blockIdx.y;
  int i0 = blockIdx.x * 4;
  int tid = threadIdx.x;
  int lane = tid & 63;
  int wid = tid >> 6;
  if (zfill) {
    int gid = (blockIdx.y * gridDim.x + blockIdx.x) * 256 + tid;  // 0..1048575
    for (int i = gid; i < BB * NN * FP; i += 1048576) T1g[i] = 0.f;
    T1c[gid] = 0.f;  // BB*NN*64 == 1048576 exactly
  }
  __shared__ float redm[4][4];
  __shared__ float reds[4][4];
  float g[EMB];
#pragma unroll
  for (int d = 0; d < EMB; d++)
    g[d] = ne1[(b * TT + t) * EMB + d] * ne2[(b * TT + t) * EMB + d];
  float c[4][EMB];
#pragma unroll
  for (int ii = 0; ii < 4; ii++)
#pragma unroll
    for (int d = 0; d < EMB; d++)
      c[ii][d] = E[(i0 + ii) * EMB + d] * g[d];
  float s[4][4];
#pragma unroll
  for (int jj = 0; jj < 4; jj++) {
    int j = jj * 256 + tid;
    float Ej[EMB];
#pragma unroll
    for (int d = 0; d < EMB; d++) Ej[d] = E[j * EMB + d];
#pragma unroll
    for (int ii = 0; ii < 4; ii++) {
      float acc = 0.f;
#pragma unroll
      for (int d = 0; d < EMB; d++) acc = fmaf(c[ii][d], Ej[d], acc);
      s[ii][jj] = fmaxf(acc, 0.f);
    }
  }
  float m4[4];
#pragma unroll
  for (int ii = 0; ii < 4; ii++) {
    float v = fmaxf(fmaxf(s[ii][0], s[ii][1]), fmaxf(s[ii][2], s[ii][3]));
#pragma unroll
    for (int off = 32; off > 0; off >>= 1) v = fmaxf(v, __shfl_xor(v, off));
    if (lane == 0) redm[wid][ii] = v;
  }
  __syncthreads();
#pragma unroll
  for (int ii = 0; ii < 4; ii++)
    m4[ii] = fmaxf(fmaxf(redm[0][ii], redm[1][ii]), fmaxf(redm[2][ii], redm[3][ii]));
  float e[4][4];
  float inv[4];
#pragma unroll
  for (int ii = 0; ii < 4; ii++) {
    float lsum = 0.f;
#pragma unroll
    for (int jj = 0; jj < 4; jj++) { e[ii][jj] = __expf(s[ii][jj] - m4[ii]); lsum += e[ii][jj]; }
#pragma unroll
    for (int off = 32; off > 0; off >>= 1) lsum += __shfl_xor(lsum, off);
    if (lane == 0) reds[wid][ii] = lsum;
  }
  __syncthreads();
#pragma unroll
  for (int ii = 0; ii < 4; ii++)
    inv[ii] = ASCALE / (reds[0][ii] + reds[1][ii] + reds[2][ii] + reds[3][ii]);
#pragma unroll
  for (int ii = 0; ii < 4; ii++) {
    size_t base = ((size_t)(b * NN) + i0 + ii) * NN;
#pragma unroll
    for (int jj = 0; jj < 4; jj++) {
      Ah[base + jj * 256 + tid] = (f16)(e[ii][jj] * inv[ii]);
    }
  }
}

// ---------------- gate spmv: 32-row tile x 96 cols, f16 A x hi/lo X, 2-way j-split ----------------
__global__ __launch_bounds__(256) void k_spmv_g(
    const f16* __restrict__ Ah,
    const f16* __restrict__ curh, const f16* __restrict__ curl, int t,
    const f16* __restrict__ hTh, const f16* __restrict__ hTl,
    float* __restrict__ Y) {
  int b = blockIdx.y;
  int i0 = blockIdx.x * 32;
  int kh = blockIdx.z;
  int tid = threadIdx.x;
  int lane = tid & 63, w = tid >> 6;
  int rg = w & 1, cg = w >> 1;
  int quad = lane >> 4, m = lane & 15;
  __shared__ __align__(16) f16 As_h[32][72];
  __shared__ __align__(16) f16 Xh[96][72];
  __shared__ __align__(16) f16 Xl[96][72];
  for (int q = tid; q < 11 * 72; q += 256) {
    int f = 85 + q / 72, j = q % 72;
    Xh[f][j] = (f16)0.f;
    Xl[f][j] = (f16)0.f;
  }
  f32x4 accH[3], accL[3];
#pragma unroll
  for (int q = 0; q < 3; q++) {
    accH[q] = (f32x4){0.f, 0.f, 0.f, 0.f};
    accL[q] = (f32x4){0.f, 0.f, 0.f, 0.f};
  }
  const f16* Ahb = Ah + ((size_t)(b * NN + i0)) * NN;
  const f16* curhb = curh + ((size_t)(b * TT + t) * DIN) * NN;
  const f16* curlb = curl + ((size_t)(b * TT + t) * DIN) * NN;
  const f16* hThb = hTh + ((size_t)b << 16);
  const f16* hTlb = hTl + ((size_t)b << 16);
  int ar = tid >> 3, ac = (tid & 7) << 3;
  for (int j0 = kh * 512; j0 < kh * 512 + 512; j0 += 64) {
    *(int4*)&As_h[ar][ac] = *(const int4*)(Ahb + (size_t)ar * NN + j0 + ac);
#pragma unroll
    for (int p = 0; p < 6; p++) {
      int ch = p * 256 + tid;
      int isl = ch >= 768 ? 1 : 0;
      int idx = ch - isl * 768;
      int row = idx >> 3, cc = (idx & 7) << 3;
      if (row < 85) {
        const f16* s = row < 21
            ? ((isl ? curlb : curhb) + ((size_t)row << 10) + j0 + cc)
            : ((isl ? hTlb : hThb) + ((size_t)(row - 21) << 10) + j0 + cc);
        f16* d = (isl ? &Xl[0][0] : &Xh[0][0]) + row * 72 + cc;
        *(int4*)d = *(const int4*)s;
      }
    }
    __syncthreads();
#pragma unroll
    for (int ks = 0; ks < 2; ks++) {
      int k0 = ks * 32 + quad * 8;
      f16x8 a_h = *(const f16x8*)&As_h[rg * 16 + m][k0];
#pragma unroll
      for (int nfi = 0; nfi < 3; nfi++) {
        int nf = cg * 3 + nfi;
        f16x8 x_h = *(const f16x8*)&Xh[nf * 16 + m][k0];
        f16x8 x_l = *(const f16x8*)&Xl[nf * 16 + m][k0];
        accH[nfi] = __builtin_amdgcn_mfma_f32_16x16x32_f16(a_h, x_h, accH[nfi], 0, 0, 0);
        accL[nfi] = __builtin_amdgcn_mfma_f32_16x16x32_f16(a_h, x_l, accL[nfi], 0, 0, 0);
      }
    }
    __syncthreads();
  }
#pragma unroll
  for (int nfi = 0; nfi < 3; nfi++) {
    int nf = cg * 3 + nfi;
#pragma unroll
    for (int reg = 0; reg < 4; reg++) {
      int row = i0 + rg * 16 + quad * 4 + reg;
      atomicAdd(&Y[((size_t)(b * NN) + row) * FP + nf * 16 + m],
                (accH[nfi][reg] + accL[nfi][reg] * INV_LSCALE) * INV_ASCALE);
    }
  }
}

// ---------------- cand spmv: 32-row tile x 64 cols (A @ (z*h)), f16 A, 2-way j-split ----------------
__global__ __launch_bounds__(256) void k_spmv_c(
    const f16* __restrict__ Ah,
    const f16* __restrict__ zhTh, const f16* __restrict__ zhTl,
    float* __restrict__ Y) {
  int b = blockIdx.y;
  int i0 = blockIdx.x * 32;
  int kh = blockIdx.z;
  int tid = threadIdx.x;
  int lane = tid & 63, w = tid >> 6;
  int rg = w & 1, cg = w >> 1;
  int quad = lane >> 4, m = lane & 15;
  __shared__ __align__(16) f16 As_h[32][72];
  __shared__ __align__(16) f16 Xh[64][72];
  __shared__ __align__(16) f16 Xl[64][72];
  f32x4 accH[2], accL[2];
#pragma unroll
  for (int q = 0; q < 2; q++) {
    accH[q] = (f32x4){0.f, 0.f, 0.f, 0.f};
    accL[q] = (f32x4){0.f, 0.f, 0.f, 0.f};
  }
  const f16* Ahb = Ah + ((size_t)(b * NN + i0)) * NN;
  const f16* zThb = zhTh + ((size_t)b << 16);
  const f16* zTlb = zhTl + ((size_t)b << 16);
  int ar = tid >> 3, ac = (tid & 7) << 3;
  for (int j0 = kh * 512; j0 < kh * 512 + 512; j0 += 64) {
    *(int4*)&As_h[ar][ac] = *(const int4*)(Ahb + (size_t)ar * NN + j0 + ac);
#pragma unroll
    for (int p = 0; p < 4; p++) {
      int ch = p * 256 + tid;
      int isl = ch >= 512 ? 1 : 0;
      int idx = ch - isl * 512;
      int row = idx >> 3, cc = (idx & 7) << 3;
      const f16* s = (isl ? zTlb : zThb) + ((size_t)row << 10) + j0 + cc;
      f16* d = (isl ? &Xl[0][0] : &Xh[0][0]) + row * 72 + cc;
      *(int4*)d = *(const int4*)s;
    }
    __syncthreads();
#pragma unroll
    for (int ks = 0; ks < 2; ks++) {
      int k0 = ks * 32 + quad * 8;
      f16x8 a_h = *(const f16x8*)&As_h[rg * 16 + m][k0];
#pragma unroll
      for (int nfi = 0; nfi < 2; nfi++) {
        int nf = cg * 2 + nfi;
        f16x8 x_h = *(const f16x8*)&Xh[nf * 16 + m][k0];
        f16x8 x_l = *(const f16x8*)&Xl[nf * 16 + m][k0];
        accH[nfi] = __builtin_amdgcn_mfma_f32_16x16x32_f16(a_h, x_h, accH[nfi], 0, 0, 0);
        accL[nfi] = __builtin_amdgcn_mfma_f32_16x16x32_f16(a_h, x_l, accL[nfi], 0, 0, 0);
      }
    }
    __syncthreads();
  }
#pragma unroll
  for (int nfi = 0; nfi < 2; nfi++) {
    int nf = cg * 2 + nfi;
#pragma unroll
    for (int reg = 0; reg < 4; reg++) {
      int row = i0 + rg * 16 + quad * 4 + reg;
      atomicAdd(&Y[(((size_t)(b * NN) + row) << 6) + nf * 16 + m],
                (accH[nfi][reg] + accL[nfi][reg] * INV_LSCALE) * INV_ASCALE);
    }
  }
}

// ---------------- per-node gate matmul via MFMA hi/lo: [16 x 176] @ [176 x 128] ----------------
// cur staged from cur2 ([n][f] layout): contiguous 42B per bi instead of 2B column gather.
__global__ __launch_bounds__(256) void k_nodemm_g(
    const f16* __restrict__ cur2h, const f16* __restrict__ cur2l, int t,
    const float* __restrict__ hb, const float* __restrict__ T1,
    const f16* __restrict__ Wh, const f16* __restrict__ Wl,
    const float* __restrict__ bg,
    float* __restrict__ r, float* __restrict__ zhb,
    f16* __restrict__ zhTh, f16* __restrict__ zhTl) {
  int n = (blockIdx.x & 7) * 128 + (blockIdx.x >> 3);  // bijective XCD swizzle
  int oc = blockIdx.y;
  int tid = threadIdx.x;
  int lane = tid & 63, w = tid >> 6;
  int quad = lane >> 4, m = lane & 15;
  __shared__ __align__(16) f16 Xh[16][200];
  __shared__ __align__(16) f16 Xl[16][200];
  for (int q = tid; q < 16 * 200; q += 256) {
    int bi = q / 200, kf = q % 200;
    f16 hi, lo;
    if (kf < DIN) {
      size_t ci = ((size_t)(bi * TT + t) * NN + n) * C2P + kf;
      hi = cur2h[ci];
      lo = cur2l[ci];
    } else if (kf < 2 * FF) {
      float v = (kf < FF) ? hb[(((size_t)bi << 10) + n) * DOUT + kf - DIN]
                          : T1[(((size_t)bi << 10) + n) * FP + kf - FF];
      hi = (f16)v;
      lo = (f16)((v - (float)hi) * LSCALE);
    } else {
      hi = (f16)0.f;
      lo = (f16)0.f;
    }
    Xh[bi][kf] = hi;
    Xl[bi][kf] = lo;
  }
  __syncthreads();
  f32x4 accH = (f32x4){0.f, 0.f, 0.f, 0.f};
  f32x4 accL = (f32x4){0.f, 0.f, 0.f, 0.f};
  const f16* WhB = Wh + ((size_t)(n * 128 + oc * 64 + w * 16 + m)) * KFP + quad * 8;
  const f16* WlB = Wl + ((size_t)(n * 128 + oc * 64 + w * 16 + m)) * KFP + quad * 8;
#pragma unroll
  for (int ks = 0; ks < 6; ks++) {
    f16x8 b_h = *(const f16x8*)(WhB + ks * 32);
    f16x8 b_l = *(const f16x8*)(WlB + ks * 32);
    int k0 = ks * 32 + quad * 8;
    f16x8 a_h = *(const f16x8*)&Xh[m][k0];
    f16x8 a_l = *(const f16x8*)&Xl[m][k0];
    accH = __builtin_amdgcn_mfma_f32_16x16x32_f16(a_h, b_h, accH, 0, 0, 0);
    accL = __builtin_amdgcn_mfma_f32_16x16x32_f16(a_h, b_l, accL, 0, 0, 0);
    accL = __builtin_amdgcn_mfma_f32_16x16x32_f16(a_l, b_h, accL, 0, 0, 0);
  }
  int o = oc * 64 + w * 16 + m;
  float bias = bg[n * 128 + o];
  if (oc == 0) {
#pragma unroll
    for (int reg = 0; reg < 4; reg++) {
      int bi = quad * 4 + reg;
      float v = accH[reg] + accL[reg] * INV_LSCALE + bias;
      v = 1.f / (1.f + __expf(-v));
      size_t off = (((size_t)bi << 10) + n) * DOUT;
      float zh = v * hb[off + o];
      zhb[off + o] = zh;
      f16 hi = (f16)zh;
      size_t ti = (((size_t)(bi * 64 + o)) << 10) + n;
      zhTh[ti] = hi;
      zhTl[ti] = (f16)((zh - (float)hi) * LSCALE);
    }
  } else {
#pragma unroll
    for (int reg = 0; reg < 4; reg++) {
      int bi = quad * 4 + reg;
      float v = accH[reg] + accL[reg] * INV_LSCALE + bias;
      v = 1.f / (1.f + __expf(-v));
      r[(((size_t)bi << 10) + n) * DOUT + o - DOUT] = v;
    }
  }
}

// ---------------- FUSED: per-node cand matmul + GRU  ||  scores(t+1) ----------------
// nodemm_c role uses cur2 ([n][f]) staging; re-zeros its T1 rows; scores role as before.
__global__ __launch_bounds__(256) void k_ncsc(
    const f16* __restrict__ cur2h, const f16* __restrict__ cur2l, int t,
    const float* __restrict__ hb_in, const float* __restrict__ zhb,
    float* __restrict__ T1g, float* __restrict__ T1c,
    const f16* __restrict__ Wh, const f16* __restrict__ Wl,
    const float* __restrict__ bc,
    const float* __restrict__ r, float* __restrict__ hb, f16* __restrict__ seqb,
    f16* __restrict__ hTh, f16* __restrict__ hTl,
    const float* __restrict__ E, const float* __restrict__ ne1,
    const float* __restrict__ ne2, f16* __restrict__ Ah) {
  int tid = threadIdx.x;
  __shared__ __align__(16) f16 Xh[16][200];
  __shared__ __align__(16) f16 Xl[16][200];
  __shared__ float redm[4][4];
  __shared__ float reds[4][4];
  if (blockIdx.x < NN) {
    // ---------- nodemm_c role ----------
    int n = (blockIdx.x & 7) * 128 + (blockIdx.x >> 3);  // bijective XCD swizzle
    int lane = tid & 63, w = tid >> 6;
    int quad = lane >> 4, m = lane & 15;
    for (int q = tid; q < 16 * 200; q += 256) {
      int bi = q / 200, kf = q % 200;
      f16 hi, lo;
      if (kf < DIN) {
        size_t ci = ((size_t)(bi * TT + t) * NN + n) * C2P + kf;
        hi = cur2h[ci];
        lo = cur2l[ci];
      } else if (kf < 2 * FF) {
        float v;
        if (kf < FF) v = zhb[(((size_t)bi << 10) + n) * DOUT + kf - DIN];
        else {
          int u = kf - FF;
          v = (u < DIN) ? T1g[(((size_t)bi << 10) + n) * FP + u]
                        : T1c[((((size_t)bi << 10) + n) << 6) + (u - DIN)];
        }
        hi = (f16)v;
        lo = (f16)((v - (float)hi) * LSCALE);
      } else {
        hi = (f16)0.f;
        lo = (f16)0.f;
      }
      Xh[bi][kf] = hi;
      Xl[bi][kf] = lo;
    }
    __syncthreads();
    // T1 rows for this n are fully consumed -> zero for next step's atomics (block-private).
    for (int q = tid; q < BB * FP; q += 256) {
      int bi = q / FP, col = q % FP;
      T1g[(((size_t)bi << 10) + n) * FP + col] = 0.f;
    }
    for (int q = tid; q < BB * DOUT; q += 256) {
      int bi = q >> 6, col = q & 63;
      T1c[((((size_t)bi << 10) + n) << 6) + col] = 0.f;
    }
    f32x4 accH = (f32x4){0.f, 0.f, 0.f, 0.f};
    f32x4 accL = (f32x4){0.f, 0.f, 0.f, 0.f};
    const f16* WhB = Wh + ((size_t)(n * 64 + w * 16 + m)) * KFP + quad * 8;
    const f16* WlB = Wl + ((size_t)(n * 64 + w * 16 + m)) * KFP + quad * 8;
#pragma unroll
    for (int ks = 0; ks < 6; ks++) {
      f16x8 b_h = *(const f16x8*)(WhB + ks * 32);
      f16x8 b_l = *(const f16x8*)(WlB + ks * 32);
      int k0 = ks * 32 + quad * 8;
      f16x8 a_h = *(const f16x8*)&Xh[m][k0];
      f16x8 a_l = *(const f16x8*)&Xl[m][k0];
      accH = __builtin_amdgcn_mfma_f32_16x16x32_f16(a_h, b_h, accH, 0, 0, 0);
      accL = __builtin_amdgcn_mfma_f32_16x16x32_f16(a_h, b_l, accL, 0, 0, 0);
      accL = __builtin_amdgcn_mfma_f32_16x16x32_f16(a_l, b_h, accL, 0, 0, 0);
    }
    int o = w * 16 + m;
    float bias = bc[n * 64 + o];
#pragma unroll
    for (int reg = 0; reg < 4; reg++) {
      int bi = quad * 4 + reg;
      float v = accH[reg] + accL[reg] * INV_LSCALE + bias;
      float hc = tanhf(v);
      size_t off = (((size_t)bi << 10) + n) * DOUT + o;
      float rv = r[off];
      float hn = rv * hb_in[off] + (1.f - rv) * hc;
      hb[off] = hn;
      seqb[((size_t)(bi * TT + t) * NN + n) * DOUT + o] = (f16)hn;
      f16 hi = (f16)hn;
      size_t ti = (((size_t)(bi * 64 + o)) << 10) + n;
      hTh[ti] = hi;
      hTl[ti] = (f16)((hn - (float)hi) * LSCALE);
    }
  } else {
    // ---------- scores role, step t+1 ----------
    int ts = t + 1;
    if (ts >= TT) return;
    int sidx = blockIdx.x - NN;          // 0..4095
    int b = sidx >> 8;
    int i0 = (sidx & 255) * 4;
    int lane = tid & 63;
    int wid = tid >> 6;
    float g[EMB];
#pragma unroll
    for (int d = 0; d < EMB; d++)
      g[d] = ne1[(b * TT + ts) * EMB + d] * ne2[(b * TT + ts) * EMB + d];
    float c[4][EMB];
#pragma unroll
    for (int ii = 0; ii < 4; ii++)
#pragma unroll
      for (int d = 0; d < EMB; d++)
        c[ii][d] = E[(i0 + ii) * EMB + d] * g[d];
    float s[4][4];
#pragma unroll
    for (int jj = 0; jj < 4; jj++) {
      int j = jj * 256 + tid;
      float Ej[EMB];
#pragma unroll
      for (int d = 0; d < EMB; d++) Ej[d] = E[j * EMB + d];
#pragma unroll
      for (int ii = 0; ii < 4; ii++) {
        float acc = 0.f;
#pragma unroll
        for (int d = 0; d < EMB; d++) acc = fmaf(c[ii][d], Ej[d], acc);
        s[ii][jj] = fmaxf(acc, 0.f);
      }
    }
    float m4[4];
#pragma unroll
    for (int ii = 0; ii < 4; ii++) {
      float v = fmaxf(fmaxf(s[ii][0], s[ii][1]), fmaxf(s[ii][2], s[ii][3]));
#pragma unroll
      for (int off = 32; off > 0; off >>= 1) v = fmaxf(v, __shfl_xor(v, off));
      if (lane == 0) redm[wid][ii] = v;
    }
    __syncthreads();
#pragma unroll
    for (int ii = 0; ii < 4; ii++)
      m4[ii] = fmaxf(fmaxf(redm[0][ii], redm[1][ii]), fmaxf(redm[2][ii], redm[3][ii]));
    float e[4][4];
    float inv[4];
#pragma unroll
    for (int ii = 0; ii < 4; ii++) {
      float lsum = 0.f;
#pragma unroll
      for (int jj = 0; jj < 4; jj++) { e[ii][jj] = __expf(s[ii][jj] - m4[ii]); lsum += e[ii][jj]; }
#pragma unroll
      for (int off = 32; off > 0; off >>= 1) lsum += __shfl_xor(lsum, off);
      if (lane == 0) reds[wid][ii] = lsum;
    }
    __syncthreads();
#pragma unroll
    for (int ii = 0; ii < 4; ii++)
      inv[ii] = ASCALE / (reds[0][ii] + reds[1][ii] + reds[2][ii] + reds[3][ii]);
#pragma unroll
    for (int ii = 0; ii < 4; ii++) {
      size_t base = ((size_t)(b * NN) + i0 + ii) * NN;
#pragma unroll
      for (int jj = 0; jj < 4; jj++) {
        Ah[base + jj * 256 + tid] = (f16)(e[ii][jj] * inv[ii]);
      }
    }
  }
}

// ---------------- QKV projection via MFMA: [196608 x 64] @ [64 x 192] ----------------
__global__ __launch_bounds__(256) void k_qkv(const f16* __restrict__ seqb,
    const f16* __restrict__ wbt, const float* __restrict__ biasb,
    f16* __restrict__ qkvb) {
  int R0 = blockIdx.x * 128;
  int tid = threadIdx.x;
  int lane = tid & 63, w = tid >> 6;
  int quad = lane >> 4, m = lane & 15;
  __shared__ __align__(16) f16 Sb[128][72];
  __shared__ __align__(16) f16 Wt[192][72];
#pragma unroll
  for (int p = 0; p < 4; p++) {
    int q = p * 256 + tid;
    int rr = q >> 3, cc = q & 7;
    *(int4*)&Sb[rr][cc * 8] = *(const int4*)&seqb[((size_t)(R0 + rr) << 6) + cc * 8];
  }
#pragma unroll
  for (int p = 0; p < 6; p++) {
    int q = p * 256 + tid;
    int rr = q >> 3, cc = q & 7;
    *(int4*)&Wt[rr][cc * 8] = *(const int4*)&wbt[((size_t)rr << 6) + cc * 8];
  }
  __syncthreads();
  f32x4 acc[2][12];
#pragma unroll
  for (int mi = 0; mi < 2; mi++)
#pragma unroll
    for (int nf = 0; nf < 12; nf++) acc[mi][nf] = (f32x4){0.f, 0.f, 0.f, 0.f};
#pragma unroll
  for (int ks = 0; ks < 2; ks++) {
    int k0 = ks * 32 + quad * 8;
    f16x8 a0 = *(const f16x8*)&Sb[w * 32 + m][k0];
    f16x8 a1 = *(const f16x8*)&Sb[w * 32 + 16 + m][k0];
#pragma unroll
    for (int nf = 0; nf < 12; nf++) {
      f16x8 bb = *(const f16x8*)&Wt[nf * 16 + m][k0];
      acc[0][nf] = __builtin_amdgcn_mfma_f32_16x16x32_f16(a0, bb, acc[0][nf], 0, 0, 0);
      acc[1][nf] = __builtin_amdgcn_mfma_f32_16x16x32_f16(a1, bb, acc[1][nf], 0, 0, 0);
    }
  }
  float bias_r[12];
#pragma unroll
  for (int nf = 0; nf < 12; nf++) bias_r[nf] = biasb[nf * 16 + m];
#pragma unroll
  for (int mi = 0; mi < 2; mi++) {
#pragma unroll
    for (int nf = 0; nf < 12; nf++) {
      int mat = nf >> 2;
      int d = (nf & 3) * 16 + m;
#pragma unroll
      for (int reg = 0; reg < 4; reg++) {
        int R = R0 + w * 32 + mi * 16 + quad * 4 + reg;
        qkvb[(size_t)mat * BTN * DOUT + ((size_t)R << 6) + d] = (f16)(acc[mi][nf][reg] + bias_r[nf]);
      }
    }
  }
}

// ---------------- temporal attention per (b,n): 4 waves/block, f16 Q/K LDS ----------------
__global__ __launch_bounds__(256) void k_attn2(const f16* __restrict__ qkvb,
    float* __restrict__ out) {
  int wv = threadIdx.x >> 6;
  int d = threadIdx.x & 63;
  int n = blockIdx.x * 4 + wv;
  int b = blockIdx.y;
  const f16* Qb = qkvb;
  const f16* Kb = qkvb + (size_t)BTN * DOUT;
  const f16* Vb = qkvb + (size_t)2 * BTN * DOUT;
  __shared__ f16 Qs[4][TT][72], Ks[4][TT][72];
  __shared__ float at[4][TT][13];
  float vr[TT];
#pragma unroll
  for (int t = 0; t < TT; t++) {
    size_t off = ((size_t)(b * TT + t) * NN + n) * DOUT + d;
    Qs[wv][t][d] = Qb[off];
    Ks[wv][t][d] = Kb[off];
    vr[t] = (float)Vb[off];
  }
  __syncthreads();
  for (int idx = d; idx < TT * TT; idx += 64) {
    int tt = idx / TT, ss = idx % TT;
    float sc = 0.f;
#pragma unroll
    for (int k = 0; k < DOUT; k++)
      sc = fmaf((float)Qs[wv][tt][k], (float)Ks[wv][ss][k], sc);
    at[wv][tt][ss] = sc * 0.125f;
  }
  __syncthreads();
  if (d < TT) {
    float mx = -1e30f;
#pragma unroll
    for (int s = 0; s < TT; s++) mx = fmaxf(mx, at[wv][d][s]);
    float sum = 0.f;
#pragma unroll
    for (int s = 0; s < TT; s++) { float e = __expf(at[wv][d][s] - mx); at[wv][d][s] = e; sum += e; }
    float inv = 1.f / sum;
#pragma unroll
    for (int s = 0; s < TT; s++) at[wv][d][s] *= inv;
  }
  __syncthreads();
  float o[TT];
#pragma unroll
  for (int t = 0; t < TT; t++) o[t] = 0.f;
#pragma unroll
  for (int s = 0; s < TT; s++) {
    float vv = vr[s];
#pragma unroll
    for (int t = 0; t < TT; t++) o[t] = fmaf(at[wv][t][s], vv, o[t]);
  }
#pragma unroll
  for (int t = 0; t < TT; t++)
    out[((size_t)(b * TT + t) * NN + n) * DOUT + d] = o[t];
}

__global__ __launch_bounds__(256) void k_hlast(const float* __restrict__ h, float* __restrict__ o) {
  int i = blockIdx.x * 256 + threadIdx.x;
  if (i < BB * NN * DOUT) o[i] = h[i];
}

extern "C" void kernel_launch(void* const* d_in, const int* in_sizes, int n_in,
                              void* d_out, int out_size, void* d_ws, size_t ws_size,
                              hipStream_t stream) {
  const float* x        = (const float*)d_in[0];
  const float* init_st  = (const float*)d_in[1];
  const float* ne_tod   = (const float*)d_in[2];
  const float* ne_dow   = (const float*)d_in[3];
  const float* E        = (const float*)d_in[4];
  const float* Wtod     = (const float*)d_in[5];
  const float* btod     = (const float*)d_in[6];
  const float* Wdow     = (const float*)d_in[7];
  const float* bdow     = (const float*)d_in[8];
  const float* WQ       = (const float*)d_in[9];
  const float* bQ       = (const float*)d_in[10];
  const float* WK       = (const float*)d_in[11];
  const float* bK       = (const float*)d_in[12];
  const float* WV       = (const float*)d_in[13];
  const float* bV       = (const float*)d_in[14];
  const float* Wpool_g  = (const float*)d_in[15];
  const float* bpool_g  = (const float*)d_in[16];
  const float* Wpool_c  = (const float*)d_in[17];
  const float* bpool_c  = (const float*)d_in[18];

  float* out = (float*)d_out;
  float* hlast_out = out + (size_t)BTN * DOUT;
  // d_out front parking (all dead before k_attn2/k_hlast write):
  //   seqb  f16 [BTN*64]           25.2 MB
  //   cur2h f16 [BTN*24]            9.4 MB   ([b][t][n][f] layout for nodemm staging)
  //   cur2l f16 [BTN*24]            9.4 MB   -> total 44.0 MB < 50.3 MB out region
  f16* seqb  = (f16*)d_out;
  f16* cur2h = seqb + (size_t)BTN * DOUT;
  f16* cur2l = cur2h + (size_t)BTN * C2P;

  char* P = (char*)d_ws;
  auto alloc = [&](size_t bytes) { char* r = P; P += (bytes + 255) & ~(size_t)255; return r; };
  f16* curh  = (f16*)alloc((size_t)BB * TT * DIN * NN * 2);   // 8.26 MB
  f16* curl  = (f16*)alloc((size_t)BB * TT * DIN * NN * 2);   // 8.26 MB
  f16* Wgh   = (f16*)alloc((size_t)NN * 128 * KFP * 2);       // 46.1 MB  [n][o][k] f16 hi
  f16* Wgl   = (f16*)alloc((size_t)NN * 128 * KFP * 2);       // 46.1 MB  lo
  f16* Wch   = (f16*)alloc((size_t)NN * 64 * KFP * 2);        // 23.1 MB
  f16* Wcl   = (f16*)alloc((size_t)NN * 64 * KFP * 2);        // 23.1 MB
  float* Wp2g = (float*)alloc((size_t)128 * 22 * EMB * 8 * 4); // 901 KB transposed pool (g)
  float* Wp2c = (float*)alloc((size_t)64 * 22 * EMB * 8 * 4);  // 450 KB transposed pool (c)
  float* bg  = (float*)alloc((size_t)NN * 128 * 4);
  float* bc  = (float*)alloc((size_t)NN * 64 * 4);
  float* hb  = (float*)alloc((size_t)BB * NN * DOUT * 4);     // 4.2 MB
  f16* wbt   = (f16*)alloc((size_t)3 * DOUT * DOUT * 2);
  float* biasb = (float*)alloc(192 * 4);
  float* rb  = (float*)alloc((size_t)BB * NN * DOUT * 4);     // 4.2 MB
  float* zhb = (float*)alloc((size_t)BB * NN * DOUT * 4);     // 4.2 MB
  f16* hTh   = (f16*)alloc((size_t)BB * DOUT * NN * 2);       // 2 MB
  f16* hTl   = (f16*)alloc((size_t)BB * DOUT * NN * 2);       // 2 MB
  f16* zhTh  = (f16*)alloc((size_t)BB * DOUT * NN * 2);       // 2 MB
  f16* zhTl  = (f16*)alloc((size_t)BB * DOUT * NN * 2);       // 2 MB
  char* LOOP = P;  // loop-scoped region, overlaid by qkvb after the loop
  f16* Ah    = (f16*)alloc((size_t)BB * NN * NN * 2);         // 33.6 MB (f16, no lo)
  float* T1g = (float*)alloc((size_t)BB * NN * FP * 4);       // 6.3 MB
  float* T1c = (float*)alloc((size_t)BB * NN * DOUT * 4);     // 4.2 MB
  f16* qkvb  = (f16*)LOOP;  // 75.5 MB overlays loop region (+ free tail)
  // footprint = fixed ~178 MB + max(loop 44.1, qkvb 75.5) ≈ 253.5 MB (< 260.6 proven)

  k_embedT<<<(BB * TT * NN + 255) / 256, 256, 0, stream>>>(x, Wtod, btod, Wdow, bdow,
                                                           curh, curl, cur2h, cur2l);
  {
    int totg = 128 * 22 * EMB * 8;
    int totc = 64 * 22 * EMB * 8;
    k_wpT<<<(totg + 255) / 256, 256, 0, stream>>>(Wpool_g, Wp2g, 128, totg);
    k_wpT<<<(totc + 255) / 256, 256, 0, stream>>>(Wpool_c, Wp2c, 64, totc);
  }
  k_poolT<<<dim3(11, 64), 256, 0, stream>>>(E, Wp2g, Wgh, Wgl, 128, 128 * 22);
  k_poolT<<<dim3(6, 64), 256, 0, stream>>>(E, Wp2c, Wch, Wcl, 64, 64 * 22);
  k_poolb<<<(NN * 128 + 255) / 256, 256, 0, stream>>>(E, bpool_g, bg, 128);
  k_poolb<<<(NN * 64 + 255) / 256, 256, 0, stream>>>(E, bpool_c, bc, 64);
  k_inith<<<(BB * NN * DOUT + 255) / 256, 256, 0, stream>>>(init_st, hb, hTh, hTl);
  k_cvtw<<<(3 * DOUT * DOUT + 192 + 255) / 256, 256, 0, stream>>>(WQ, WK, WV, bQ, bK, bV, wbt, biasb);

  // scores for t=0 (with T1 zero-fill); subsequent scores are fused into k_ncsc.
  k_scores<<<dim3(NN / 4, BB), 256, 0, stream>>>(E, ne_tod, ne_dow, 0, Ah, T1g, T1c, 1);
  for (int t = 0; t < TT; t++) {
    k_spmv_g<<<dim3(NN / 32, BB, 2), 256, 0, stream>>>(Ah, curh, curl, t, hTh, hTl, T1g);
    k_nodemm_g<<<dim3(NN, 2), 256, 0, stream>>>(cur2h, cur2l, t, hb, T1g, Wgh, Wgl, bg, rb, zhb, zhTh, zhTl);
    k_spmv_c<<<dim3(NN / 32, BB, 2), 256, 0, stream>>>(Ah, zhTh, zhTl, T1c);
    k_ncsc<<<NN + (NN / 4) * BB, 256, 0, stream>>>(cur2h, cur2l, t, hb, zhb, T1g, T1c,
        Wch, Wcl, bc, rb, hb, seqb, hTh, hTl, E, ne_tod, ne_dow, Ah);
  }

  k_qkv<<<BTN / 128, 256, 0, stream>>>(seqb, wbt, biasb, qkvb);
  k_attn2<<<dim3(NN / 4, BB), 256, 0, stream>>>(qkvb, out);
  k_hlast<<<(BB * NN * DOUT + 255) / 256, 256, 0, stream>>>(hb, hlast_out);
}

// Round 15
// 1670.691 us; speedup vs baseline: 1.0218x; 1.0218x over previous
//
#include <hip/hip_runtime.h>

#define BB 16
#define TT 12
#define NN 1024
#define EMB 10
#define DIN 21
#define DOUT 64
#define FF 85      // DIN + DOUT
#define FP 96      // padded feature stride (gate spmv output cols)
#define KFP 176    // padded 2*FF (=170) for per-node matmul K dim (6 MFMA K-steps of 32)
#define BTN (BB * TT * NN)
#define ASCALE 256.0f
#define INV_ASCALE (1.0f / 256.0f)
#define LSCALE 4096.0f
#define INV_LSCALE (1.0f / 4096.0f)

typedef float4 f4;
typedef _Float16 f16;
typedef __attribute__((ext_vector_type(8))) _Float16 f16x8;
typedef __attribute__((ext_vector_type(4))) float f32x4;

// ---------------- cur hi/lo f16, transposed [b][t][f(21)][n] ----------------
__global__ __launch_bounds__(256) void k_embedT(const float* __restrict__ x,
    const float* __restrict__ Wtod, const float* __restrict__ btod,
    const float* __restrict__ Wdow, const float* __restrict__ bdow,
    f16* __restrict__ curh, f16* __restrict__ curl) {
  int idx = blockIdx.x * 256 + threadIdx.x;
  if (idx >= BB * TT * DIN * NN) return;
  int n = idx & 1023;
  int f = (idx >> 10) % DIN;
  int bt = idx / (DIN * 1024);
  const float* xp = x + ((size_t)bt * 1024 + n) * 3;
  float v;
  if (f == 0) v = xp[0];
  else if (f < 1 + EMB) {
    int tod = (int)xp[1];
    v = Wtod[tod * EMB + f - 1] + btod[f - 1];
  } else {
    int dow = (int)xp[2];
    v = Wdow[dow * EMB + f - 1 - EMB] + bdow[f - 1 - EMB];
  }
  f16 hi = (f16)v;
  curh[idx] = hi;
  curl[idx] = (f16)((v - (float)hi) * LSCALE);
}

// ---------------- Wpool transpose: [d][kf][o] -> Wp2[o][kc][d][j(8)], kf>=170 zeroed ----------------
__global__ __launch_bounds__(256) void k_wpT(const float* __restrict__ Wpool,
    float* __restrict__ Wp2, int O, int total) {
  int idx = blockIdx.x * 256 + threadIdx.x;
  if (idx >= total) return;
  int j = idx & 7;
  int d = (idx >> 3) % EMB;
  int kc = (idx / (8 * EMB)) % 22;
  int o = idx / (8 * EMB * 22);
  int kf = kc * 8 + j;
  Wp2[idx] = (kf < 2 * FF) ? Wpool[((size_t)d * 2 * FF + kf) * O + o] : 0.f;
}

// ---------------- pooled weights f16 hi/lo, MFMA layout W[n][o][k(176)] ----------------
__global__ __launch_bounds__(256) void k_poolT(const float* __restrict__ E,
    const float* __restrict__ Wp2, f16* __restrict__ Wh, f16* __restrict__ Wl,
    int O, int CH) {
  int n0 = blockIdx.y * 16;
  int c = blockIdx.x * 256 + threadIdx.x;
  __shared__ float Es[16][EMB];
  if (threadIdx.x < 16 * EMB)
    Es[threadIdx.x / EMB][threadIdx.x % EMB] =
        E[(n0 + threadIdx.x / EMB) * EMB + threadIdx.x % EMB];
  __syncthreads();
  if (c >= CH) return;
  const float* wb = Wp2 + (size_t)c * 80;
  float wv[80];
#pragma unroll
  for (int i = 0; i < 20; i++) *(f4*)&wv[i * 4] = *(const f4*)(wb + i * 4);
  for (int ni = 0; ni < 16; ni++) {
    f16x8 hv, lv;
#pragma unroll
    for (int j = 0; j < 8; j++) {
      float v = 0.f;
#pragma unroll
      for (int d = 0; d < EMB; d++) v = fmaf(Es[ni][d], wv[d * 8 + j], v);
      f16 hi = (f16)v;
      hv[j] = hi;
      lv[j] = (f16)((v - (float)hi) * LSCALE);
    }
    size_t base = ((size_t)(n0 + ni) * O * 22 + c) * 8;
    *(f16x8*)(Wh + base) = hv;
    *(f16x8*)(Wl + base) = lv;
  }
}

__global__ __launch_bounds__(256) void k_poolb(const float* __restrict__ E,
    const float* __restrict__ bpool, float* __restrict__ bvec, int O) {
  int idx = blockIdx.x * 256 + threadIdx.x;
  if (idx >= NN * O) return;
  int o = idx % O, n = idx / O;
  float a = 0.f;
#pragma unroll
  for (int d = 0; d < EMB; d++) a += E[n * EMB + d] * bpool[d * O + o];
  bvec[idx] = a;
}

// init h + transposed hi/lo h
__global__ __launch_bounds__(256) void k_inith(const float* __restrict__ s,
    float* __restrict__ hb, f16* __restrict__ hTh, f16* __restrict__ hTl) {
  int i = blockIdx.x * 256 + threadIdx.x;
  if (i >= BB * NN * DOUT) return;
  float v = s[i];
  hb[i] = v;
  int b = i >> 16;
  int n = (i >> 6) & 1023;
  int o = i & 63;
  f16 hi = (f16)v;
  size_t ti = (((size_t)(b * 64 + o)) << 10) + n;
  hTh[ti] = hi;
  hTl[ti] = (f16)((v - (float)hi) * LSCALE);
}

// ---------------- W_QKV -> wbt[3][d][k] f16 + biasb[192] ----------------
__global__ __launch_bounds__(256) void k_cvtw(const float* __restrict__ WQ,
    const float* __restrict__ WK, const float* __restrict__ WV,
    const float* __restrict__ bQ, const float* __restrict__ bK, const float* __restrict__ bV,
    f16* __restrict__ wbt, float* __restrict__ biasb) {
  int idx = blockIdx.x * 256 + threadIdx.x;
  if (idx < 3 * DOUT * DOUT) {
    int mat = idx >> 12;
    int d = (idx >> 6) & 63;
    int k = idx & 63;
    const float* W = mat == 0 ? WQ : (mat == 1 ? WK : WV);
    wbt[idx] = (f16)(W[k * DOUT + d]);
  } else if (idx < 3 * DOUT * DOUT + 192) {
    int j = idx - 3 * DOUT * DOUT;
    const float* bb = (j >> 6) == 0 ? bQ : ((j >> 6) == 1 ? bK : bV);
    biasb[j] = bb[j & 63];
  }
}

// ---------------- A = softmax(relu(scores))*256 -> Ah (plain f16) ----------------
// zfill=1 (t=0 only): also zero-fills T1g/T1c for the first step's atomics.
__global__ __launch_bounds__(256) void k_scores(const float* __restrict__ E,
    const float* __restrict__ ne1, const float* __restrict__ ne2, int t,
    f16* __restrict__ Ah,
    float* __restrict__ T1g, float* __restrict__ T1c, int zfill) {
  int b = blockIdx.y;
  int i0 = blockIdx.x * 4;
  int tid = threadIdx.x;
  int lane = tid & 63;
  int wid = tid >> 6;
  if (zfill) {
    int gid = (blockIdx.y * gridDim.x + blockIdx.x) * 256 + tid;  // 0..1048575
    for (int i = gid; i < BB * NN * FP; i += 1048576) T1g[i] = 0.f;
    T1c[gid] = 0.f;  // BB*NN*64 == 1048576 exactly
  }
  __shared__ float redm[4][4];
  __shared__ float reds[4][4];
  float g[EMB];
#pragma unroll
  for (int d = 0; d < EMB; d++)
    g[d] = ne1[(b * TT + t) * EMB + d] * ne2[(b * TT + t) * EMB + d];
  float c[4][EMB];
#pragma unroll
  for (int ii = 0; ii < 4; ii++)
#pragma unroll
    for (int d = 0; d < EMB; d++)
      c[ii][d] = E[(i0 + ii) * EMB + d] * g[d];
  float s[4][4];
#pragma unroll
  for (int jj = 0; jj < 4; jj++) {
    int j = jj * 256 + tid;
    float Ej[EMB];
#pragma unroll
    for (int d = 0; d < EMB; d++) Ej[d] = E[j * EMB + d];
#pragma unroll
    for (int ii = 0; ii < 4; ii++) {
      float acc = 0.f;
#pragma unroll
      for (int d = 0; d < EMB; d++) acc = fmaf(c[ii][d], Ej[d], acc);
      s[ii][jj] = fmaxf(acc, 0.f);
    }
  }
  float m4[4];
#pragma unroll
  for (int ii = 0; ii < 4; ii++) {
    float v = fmaxf(fmaxf(s[ii][0], s[ii][1]), fmaxf(s[ii][2], s[ii][3]));
#pragma unroll
    for (int off = 32; off > 0; off >>= 1) v = fmaxf(v, __shfl_xor(v, off));
    if (lane == 0) redm[wid][ii] = v;
  }
  __syncthreads();
#pragma unroll
  for (int ii = 0; ii < 4; ii++)
    m4[ii] = fmaxf(fmaxf(redm[0][ii], redm[1][ii]), fmaxf(redm[2][ii], redm[3][ii]));
  float e[4][4];
  float inv[4];
#pragma unroll
  for (int ii = 0; ii < 4; ii++) {
    float lsum = 0.f;
#pragma unroll
    for (int jj = 0; jj < 4; jj++) { e[ii][jj] = __expf(s[ii][jj] - m4[ii]); lsum += e[ii][jj]; }
#pragma unroll
    for (int off = 32; off > 0; off >>= 1) lsum += __shfl_xor(lsum, off);
    if (lane == 0) reds[wid][ii] = lsum;
  }
  __syncthreads();
#pragma unroll
  for (int ii = 0; ii < 4; ii++)
    inv[ii] = ASCALE / (reds[0][ii] + reds[1][ii] + reds[2][ii] + reds[3][ii]);
#pragma unroll
  for (int ii = 0; ii < 4; ii++) {
    size_t base = ((size_t)(b * NN) + i0 + ii) * NN;
#pragma unroll
    for (int jj = 0; jj < 4; jj++) {
      Ah[base + jj * 256 + tid] = (f16)(e[ii][jj] * inv[ii]);
    }
  }
}

// ---------------- gate spmv: 32-row tile x 96 cols, f16 A x hi/lo X, 2-way j-split ----------------
// 1-D grid 1024 with XCD-group decode: all 32 blocks sharing (b,kh) — which read the SAME
// cur/hT X stream — land on one dispatch-slot residue mod 8 (= one XCD L2), eliminating
// up to 8x duplicated X fetch across the per-XCD L2s. Bijective; output bit-identical.
__global__ __launch_bounds__(256) void k_spmv_g(
    const f16* __restrict__ Ah,
    const f16* __restrict__ curh, const f16* __restrict__ curl, int t,
    const f16* __restrict__ hTh, const f16* __restrict__ hTl,
    float* __restrict__ Y) {
  int fid = blockIdx.x;
  int g = (fid & 7) + ((fid >> 8) << 3);   // group in [0,32): g = b*2+kh
  int b = g >> 1;
  int kh = g & 1;
  int i0 = ((fid >> 3) & 31) << 5;
  int tid = threadIdx.x;
  int lane = tid & 63, w = tid >> 6;
  int rg = w & 1, cg = w >> 1;
  int quad = lane >> 4, m = lane & 15;
  __shared__ __align__(16) f16 As_h[32][72];
  __shared__ __align__(16) f16 Xh[96][72];
  __shared__ __align__(16) f16 Xl[96][72];
  for (int q = tid; q < 11 * 72; q += 256) {
    int f = 85 + q / 72, j = q % 72;
    Xh[f][j] = (f16)0.f;
    Xl[f][j] = (f16)0.f;
  }
  f32x4 accH[3], accL[3];
#pragma unroll
  for (int q = 0; q < 3; q++) {
    accH[q] = (f32x4){0.f, 0.f, 0.f, 0.f};
    accL[q] = (f32x4){0.f, 0.f, 0.f, 0.f};
  }
  const f16* Ahb = Ah + ((size_t)(b * NN + i0)) * NN;
  const f16* curhb = curh + ((size_t)(b * TT + t) * DIN) * NN;
  const f16* curlb = curl + ((size_t)(b * TT + t) * DIN) * NN;
  const f16* hThb = hTh + ((size_t)b << 16);
  const f16* hTlb = hTl + ((size_t)b << 16);
  int ar = tid >> 3, ac = (tid & 7) << 3;
  for (int j0 = kh * 512; j0 < kh * 512 + 512; j0 += 64) {
    *(int4*)&As_h[ar][ac] = *(const int4*)(Ahb + (size_t)ar * NN + j0 + ac);
#pragma unroll
    for (int p = 0; p < 6; p++) {
      int ch = p * 256 + tid;
      int isl = ch >= 768 ? 1 : 0;
      int idx = ch - isl * 768;
      int row = idx >> 3, cc = (idx & 7) << 3;
      if (row < 85) {
        const f16* s = row < 21
            ? ((isl ? curlb : curhb) + ((size_t)row << 10) + j0 + cc)
            : ((isl ? hTlb : hThb) + ((size_t)(row - 21) << 10) + j0 + cc);
        f16* d = (isl ? &Xl[0][0] : &Xh[0][0]) + row * 72 + cc;
        *(int4*)d = *(const int4*)s;
      }
    }
    __syncthreads();
#pragma unroll
    for (int ks = 0; ks < 2; ks++) {
      int k0 = ks * 32 + quad * 8;
      f16x8 a_h = *(const f16x8*)&As_h[rg * 16 + m][k0];
#pragma unroll
      for (int nfi = 0; nfi < 3; nfi++) {
        int nf = cg * 3 + nfi;
        f16x8 x_h = *(const f16x8*)&Xh[nf * 16 + m][k0];
        f16x8 x_l = *(const f16x8*)&Xl[nf * 16 + m][k0];
        accH[nfi] = __builtin_amdgcn_mfma_f32_16x16x32_f16(a_h, x_h, accH[nfi], 0, 0, 0);
        accL[nfi] = __builtin_amdgcn_mfma_f32_16x16x32_f16(a_h, x_l, accL[nfi], 0, 0, 0);
      }
    }
    __syncthreads();
  }
#pragma unroll
  for (int nfi = 0; nfi < 3; nfi++) {
    int nf = cg * 3 + nfi;
#pragma unroll
    for (int reg = 0; reg < 4; reg++) {
      int row = i0 + rg * 16 + quad * 4 + reg;
      atomicAdd(&Y[((size_t)(b * NN) + row) * FP + nf * 16 + m],
                (accH[nfi][reg] + accL[nfi][reg] * INV_LSCALE) * INV_ASCALE);
    }
  }
}

// ---------------- cand spmv: 32-row tile x 64 cols (A @ (z*h)), f16 A, XCD-group decode ----------------
__global__ __launch_bounds__(256) void k_spmv_c(
    const f16* __restrict__ Ah,
    const f16* __restrict__ zhTh, const f16* __restrict__ zhTl,
    float* __restrict__ Y) {
  int fid = blockIdx.x;
  int g = (fid & 7) + ((fid >> 8) << 3);
  int b = g >> 1;
  int kh = g & 1;
  int i0 = ((fid >> 3) & 31) << 5;
  int tid = threadIdx.x;
  int lane = tid & 63, w = tid >> 6;
  int rg = w & 1, cg = w >> 1;
  int quad = lane >> 4, m = lane & 15;
  __shared__ __align__(16) f16 As_h[32][72];
  __shared__ __align__(16) f16 Xh[64][72];
  __shared__ __align__(16) f16 Xl[64][72];
  f32x4 accH[2], accL[2];
#pragma unroll
  for (int q = 0; q < 2; q++) {
    accH[q] = (f32x4){0.f, 0.f, 0.f, 0.f};
    accL[q] = (f32x4){0.f, 0.f, 0.f, 0.f};
  }
  const f16* Ahb = Ah + ((size_t)(b * NN + i0)) * NN;
  const f16* zThb = zhTh + ((size_t)b << 16);
  const f16* zTlb = zhTl + ((size_t)b << 16);
  int ar = tid >> 3, ac = (tid & 7) << 3;
  for (int j0 = kh * 512; j0 < kh * 512 + 512; j0 += 64) {
    *(int4*)&As_h[ar][ac] = *(const int4*)(Ahb + (size_t)ar * NN + j0 + ac);
#pragma unroll
    for (int p = 0; p < 4; p++) {
      int ch = p * 256 + tid;
      int isl = ch >= 512 ? 1 : 0;
      int idx = ch - isl * 512;
      int row = idx >> 3, cc = (idx & 7) << 3;
      const f16* s = (isl ? zTlb : zThb) + ((size_t)row << 10) + j0 + cc;
      f16* d = (isl ? &Xl[0][0] : &Xh[0][0]) + row * 72 + cc;
      *(int4*)d = *(const int4*)s;
    }
    __syncthreads();
#pragma unroll
    for (int ks = 0; ks < 2; ks++) {
      int k0 = ks * 32 + quad * 8;
      f16x8 a_h = *(const f16x8*)&As_h[rg * 16 + m][k0];
#pragma unroll
      for (int nfi = 0; nfi < 2; nfi++) {
        int nf = cg * 2 + nfi;
        f16x8 x_h = *(const f16x8*)&Xh[nf * 16 + m][k0];
        f16x8 x_l = *(const f16x8*)&Xl[nf * 16 + m][k0];
        accH[nfi] = __builtin_amdgcn_mfma_f32_16x16x32_f16(a_h, x_h, accH[nfi], 0, 0, 0);
        accL[nfi] = __builtin_amdgcn_mfma_f32_16x16x32_f16(a_h, x_l, accL[nfi], 0, 0, 0);
      }
    }
    __syncthreads();
  }
#pragma unroll
  for (int nfi = 0; nfi < 2; nfi++) {
    int nf = cg * 2 + nfi;
#pragma unroll
    for (int reg = 0; reg < 4; reg++) {
      int row = i0 + rg * 16 + quad * 4 + reg;
      atomicAdd(&Y[(((size_t)(b * NN) + row) << 6) + nf * 16 + m],
                (accH[nfi][reg] + accL[nfi][reg] * INV_LSCALE) * INV_ASCALE);
    }
  }
}

// ---------------- per-node gate matmul via MFMA hi/lo: [16 x 176] @ [176 x 128] ----------------
__global__ __launch_bounds__(256) void k_nodemm_g(
    const f16* __restrict__ curh, const f16* __restrict__ curl, int t,
    const float* __restrict__ hb, const float* __restrict__ T1,
    const f16* __restrict__ Wh, const f16* __restrict__ Wl,
    const float* __restrict__ bg,
    float* __restrict__ r, float* __restrict__ zhb,
    f16* __restrict__ zhTh, f16* __restrict__ zhTl) {
  int n = (blockIdx.x & 7) * 128 + (blockIdx.x >> 3);  // bijective XCD swizzle
  int oc = blockIdx.y;
  int tid = threadIdx.x;
  int lane = tid & 63, w = tid >> 6;
  int quad = lane >> 4, m = lane & 15;
  __shared__ __align__(16) f16 Xh[16][200];
  __shared__ __align__(16) f16 Xl[16][200];
  for (int q = tid; q < 16 * 200; q += 256) {
    int bi = q / 200, kf = q % 200;
    f16 hi, lo;
    if (kf < DIN) {
      size_t ci = (((size_t)(bi * TT + t) * DIN) + kf) * NN + n;
      hi = curh[ci];
      lo = curl[ci];
    } else if (kf < 2 * FF) {
      float v = (kf < FF) ? hb[(((size_t)bi << 10) + n) * DOUT + kf - DIN]
                          : T1[(((size_t)bi << 10) + n) * FP + kf - FF];
      hi = (f16)v;
      lo = (f16)((v - (float)hi) * LSCALE);
    } else {
      hi = (f16)0.f;
      lo = (f16)0.f;
    }
    Xh[bi][kf] = hi;
    Xl[bi][kf] = lo;
  }
  __syncthreads();
  f32x4 accH = (f32x4){0.f, 0.f, 0.f, 0.f};
  f32x4 accL = (f32x4){0.f, 0.f, 0.f, 0.f};
  const f16* WhB = Wh + ((size_t)(n * 128 + oc * 64 + w * 16 + m)) * KFP + quad * 8;
  const f16* WlB = Wl + ((size_t)(n * 128 + oc * 64 + w * 16 + m)) * KFP + quad * 8;
#pragma unroll
  for (int ks = 0; ks < 6; ks++) {
    f16x8 b_h = *(const f16x8*)(WhB + ks * 32);
    f16x8 b_l = *(const f16x8*)(WlB + ks * 32);
    int k0 = ks * 32 + quad * 8;
    f16x8 a_h = *(const f16x8*)&Xh[m][k0];
    f16x8 a_l = *(const f16x8*)&Xl[m][k0];
    accH = __builtin_amdgcn_mfma_f32_16x16x32_f16(a_h, b_h, accH, 0, 0, 0);
    accL = __builtin_amdgcn_mfma_f32_16x16x32_f16(a_h, b_l, accL, 0, 0, 0);
    accL = __builtin_amdgcn_mfma_f32_16x16x32_f16(a_l, b_h, accL, 0, 0, 0);
  }
  int o = oc * 64 + w * 16 + m;
  float bias = bg[n * 128 + o];
  if (oc == 0) {
#pragma unroll
    for (int reg = 0; reg < 4; reg++) {
      int bi = quad * 4 + reg;
      float v = accH[reg] + accL[reg] * INV_LSCALE + bias;
      v = 1.f / (1.f + __expf(-v));
      size_t off = (((size_t)bi << 10) + n) * DOUT;
      float zh = v * hb[off + o];
      zhb[off + o] = zh;
      f16 hi = (f16)zh;
      size_t ti = (((size_t)(bi * 64 + o)) << 10) + n;
      zhTh[ti] = hi;
      zhTl[ti] = (f16)((zh - (float)hi) * LSCALE);
    }
  } else {
#pragma unroll
    for (int reg = 0; reg < 4; reg++) {
      int bi = quad * 4 + reg;
      float v = accH[reg] + accL[reg] * INV_LSCALE + bias;
      v = 1.f / (1.f + __expf(-v));
      r[(((size_t)bi << 10) + n) * DOUT + o - DOUT] = v;
    }
  }
}

// ---------------- FUSED: per-node cand matmul + GRU  ||  scores(t+1) ----------------
__global__ __launch_bounds__(256) void k_ncsc(
    const f16* __restrict__ curh, const f16* __restrict__ curl, int t,
    const float* __restrict__ hb_in, const float* __restrict__ zhb,
    float* __restrict__ T1g, float* __restrict__ T1c,
    const f16* __restrict__ Wh, const f16* __restrict__ Wl,
    const float* __restrict__ bc,
    const float* __restrict__ r, float* __restrict__ hb, f16* __restrict__ seqb,
    f16* __restrict__ hTh, f16* __restrict__ hTl,
    const float* __restrict__ E, const float* __restrict__ ne1,
    const float* __restrict__ ne2, f16* __restrict__ Ah) {
  int tid = threadIdx.x;
  __shared__ __align__(16) f16 Xh[16][200];
  __shared__ __align__(16) f16 Xl[16][200];
  __shared__ float redm[4][4];
  __shared__ float reds[4][4];
  if (blockIdx.x < NN) {
    // ---------- nodemm_c role ----------
    int n = (blockIdx.x & 7) * 128 + (blockIdx.x >> 3);  // bijective XCD swizzle
    int lane = tid & 63, w = tid >> 6;
    int quad = lane >> 4, m = lane & 15;
    for (int q = tid; q < 16 * 200; q += 256) {
      int bi = q / 200, kf = q % 200;
      f16 hi, lo;
      if (kf < DIN) {
        size_t ci = (((size_t)(bi * TT + t) * DIN) + kf) * NN + n;
        hi = curh[ci];
        lo = curl[ci];
      } else if (kf < 2 * FF) {
        float v;
        if (kf < FF) v = zhb[(((size_t)bi << 10) + n) * DOUT + kf - DIN];
        else {
          int u = kf - FF;
          v = (u < DIN) ? T1g[(((size_t)bi << 10) + n) * FP + u]
                        : T1c[((((size_t)bi << 10) + n) << 6) + (u - DIN)];
        }
        hi = (f16)v;
        lo = (f16)((v - (float)hi) * LSCALE);
      } else {
        hi = (f16)0.f;
        lo = (f16)0.f;
      }
      Xh[bi][kf] = hi;
      Xl[bi][kf] = lo;
    }
    __syncthreads();
    // T1 rows for this n are fully consumed -> zero for next step's atomics (block-private).
    for (int q = tid; q < BB * FP; q += 256) {
      int bi = q / FP, col = q % FP;
      T1g[(((size_t)bi << 10) + n) * FP + col] = 0.f;
    }
    for (int q = tid; q < BB * DOUT; q += 256) {
      int bi = q >> 6, col = q & 63;
      T1c[((((size_t)bi << 10) + n) << 6) + col] = 0.f;
    }
    f32x4 accH = (f32x4){0.f, 0.f, 0.f, 0.f};
    f32x4 accL = (f32x4){0.f, 0.f, 0.f, 0.f};
    const f16* WhB = Wh + ((size_t)(n * 64 + w * 16 + m)) * KFP + quad * 8;
    const f16* WlB = Wl + ((size_t)(n * 64 + w * 16 + m)) * KFP + quad * 8;
#pragma unroll
    for (int ks = 0; ks < 6; ks++) {
      f16x8 b_h = *(const f16x8*)(WhB + ks * 32);
      f16x8 b_l = *(const f16x8*)(WlB + ks * 32);
      int k0 = ks * 32 + quad * 8;
      f16x8 a_h = *(const f16x8*)&Xh[m][k0];
      f16x8 a_l = *(const f16x8*)&Xl[m][k0];
      accH = __builtin_amdgcn_mfma_f32_16x16x32_f16(a_h, b_h, accH, 0, 0, 0);
      accL = __builtin_amdgcn_mfma_f32_16x16x32_f16(a_h, b_l, accL, 0, 0, 0);
      accL = __builtin_amdgcn_mfma_f32_16x16x32_f16(a_l, b_h, accL, 0, 0, 0);
    }
    int o = w * 16 + m;
    float bias = bc[n * 64 + o];
#pragma unroll
    for (int reg = 0; reg < 4; reg++) {
      int bi = quad * 4 + reg;
      float v = accH[reg] + accL[reg] * INV_LSCALE + bias;
      float hc = tanhf(v);
      size_t off = (((size_t)bi << 10) + n) * DOUT + o;
      float rv = r[off];
      float hn = rv * hb_in[off] + (1.f - rv) * hc;
      hb[off] = hn;
      seqb[((size_t)(bi * TT + t) * NN + n) * DOUT + o] = (f16)hn;
      f16 hi = (f16)hn;
      size_t ti = (((size_t)(bi * 64 + o)) << 10) + n;
      hTh[ti] = hi;
      hTl[ti] = (f16)((hn - (float)hi) * LSCALE);
    }
  } else {
    // ---------- scores role, step t+1 ----------
    int ts = t + 1;
    if (ts >= TT) return;
    int sidx = blockIdx.x - NN;          // 0..4095
    int b = sidx >> 8;
    int i0 = (sidx & 255) * 4;
    int lane = tid & 63;
    int wid = tid >> 6;
    float g[EMB];
#pragma unroll
    for (int d = 0; d < EMB; d++)
      g[d] = ne1[(b * TT + ts) * EMB + d] * ne2[(b * TT + ts) * EMB + d];
    float c[4][EMB];
#pragma unroll
    for (int ii = 0; ii < 4; ii++)
#pragma unroll
      for (int d = 0; d < EMB; d++)
        c[ii][d] = E[(i0 + ii) * EMB + d] * g[d];
    float s[4][4];
#pragma unroll
    for (int jj = 0; jj < 4; jj++) {
      int j = jj * 256 + tid;
      float Ej[EMB];
#pragma unroll
      for (int d = 0; d < EMB; d++) Ej[d] = E[j * EMB + d];
#pragma unroll
      for (int ii = 0; ii < 4; ii++) {
        float acc = 0.f;
#pragma unroll
        for (int d = 0; d < EMB; d++) acc = fmaf(c[ii][d], Ej[d], acc);
        s[ii][jj] = fmaxf(acc, 0.f);
      }
    }
    float m4[4];
#pragma unroll
    for (int ii = 0; ii < 4; ii++) {
      float v = fmaxf(fmaxf(s[ii][0], s[ii][1]), fmaxf(s[ii][2], s[ii][3]));
#pragma unroll
      for (int off = 32; off > 0; off >>= 1) v = fmaxf(v, __shfl_xor(v, off));
      if (lane == 0) redm[wid][ii] = v;
    }
    __syncthreads();
#pragma unroll
    for (int ii = 0; ii < 4; ii++)
      m4[ii] = fmaxf(fmaxf(redm[0][ii], redm[1][ii]), fmaxf(redm[2][ii], redm[3][ii]));
    float e[4][4];
    float inv[4];
#pragma unroll
    for (int ii = 0; ii < 4; ii++) {
      float lsum = 0.f;
#pragma unroll
      for (int jj = 0; jj < 4; jj++) { e[ii][jj] = __expf(s[ii][jj] - m4[ii]); lsum += e[ii][jj]; }
#pragma unroll
      for (int off = 32; off > 0; off >>= 1) lsum += __shfl_xor(lsum, off);
      if (lane == 0) reds[wid][ii] = lsum;
    }
    __syncthreads();
#pragma unroll
    for (int ii = 0; ii < 4; ii++)
      inv[ii] = ASCALE / (reds[0][ii] + reds[1][ii] + reds[2][ii] + reds[3][ii]);
#pragma unroll
    for (int ii = 0; ii < 4; ii++) {
      size_t base = ((size_t)(b * NN) + i0 + ii) * NN;
#pragma unroll
      for (int jj = 0; jj < 4; jj++) {
        Ah[base + jj * 256 + tid] = (f16)(e[ii][jj] * inv[ii]);
      }
    }
  }
}

// ---------------- QKV projection via MFMA: [196608 x 64] @ [64 x 192] ----------------
__global__ __launch_bounds__(256) void k_qkv(const f16* __restrict__ seqb,
    const f16* __restrict__ wbt, const float* __restrict__ biasb,
    f16* __restrict__ qkvb) {
  int R0 = blockIdx.x * 128;
  int tid = threadIdx.x;
  int lane = tid & 63, w = tid >> 6;
  int quad = lane >> 4, m = lane & 15;
  __shared__ __align__(16) f16 Sb[128][72];
  __shared__ __align__(16) f16 Wt[192][72];
#pragma unroll
  for (int p = 0; p < 4; p++) {
    int q = p * 256 + tid;
    int rr = q >> 3, cc = q & 7;
    *(int4*)&Sb[rr][cc * 8] = *(const int4*)&seqb[((size_t)(R0 + rr) << 6) + cc * 8];
  }
#pragma unroll
  for (int p = 0; p < 6; p++) {
    int q = p * 256 + tid;
    int rr = q >> 3, cc = q & 7;
    *(int4*)&Wt[rr][cc * 8] = *(const int4*)&wbt[((size_t)rr << 6) + cc * 8];
  }
  __syncthreads();
  f32x4 acc[2][12];
#pragma unroll
  for (int mi = 0; mi < 2; mi++)
#pragma unroll
    for (int nf = 0; nf < 12; nf++) acc[mi][nf] = (f32x4){0.f, 0.f, 0.f, 0.f};
#pragma unroll
  for (int ks = 0; ks < 2; ks++) {
    int k0 = ks * 32 + quad * 8;
    f16x8 a0 = *(const f16x8*)&Sb[w * 32 + m][k0];
    f16x8 a1 = *(const f16x8*)&Sb[w * 32 + 16 + m][k0];
#pragma unroll
    for (int nf = 0; nf < 12; nf++) {
      f16x8 bb = *(const f16x8*)&Wt[nf * 16 + m][k0];
      acc[0][nf] = __builtin_amdgcn_mfma_f32_16x16x32_f16(a0, bb, acc[0][nf], 0, 0, 0);
      acc[1][nf] = __builtin_amdgcn_mfma_f32_16x16x32_f16(a1, bb, acc[1][nf], 0, 0, 0);
    }
  }
  float bias_r[12];
#pragma unroll
  for (int nf = 0; nf < 12; nf++) bias_r[nf] = biasb[nf * 16 + m];
#pragma unroll
  for (int mi = 0; mi < 2; mi++) {
#pragma unroll
    for (int nf = 0; nf < 12; nf++) {
      int mat = nf >> 2;
      int d = (nf & 3) * 16 + m;
#pragma unroll
      for (int reg = 0; reg < 4; reg++) {
        int R = R0 + w * 32 + mi * 16 + quad * 4 + reg;
        qkvb[(size_t)mat * BTN * DOUT + ((size_t)R << 6) + d] = (f16)(acc[mi][nf][reg] + bias_r[nf]);
      }
    }
  }
}

// ---------------- temporal attention per (b,n): 4 waves/block, f16 Q/K LDS ----------------
__global__ __launch_bounds__(256) void k_attn2(const f16* __restrict__ qkvb,
    float* __restrict__ out) {
  int wv = threadIdx.x >> 6;
  int d = threadIdx.x & 63;
  int n = blockIdx.x * 4 + wv;
  int b = blockIdx.y;
  const f16* Qb = qkvb;
  const f16* Kb = qkvb + (size_t)BTN * DOUT;
  const f16* Vb = qkvb + (size_t)2 * BTN * DOUT;
  __shared__ f16 Qs[4][TT][72], Ks[4][TT][72];
  __shared__ float at[4][TT][13];
  float vr[TT];
#pragma unroll
  for (int t = 0; t < TT; t++) {
    size_t off = ((size_t)(b * TT + t) * NN + n) * DOUT + d;
    Qs[wv][t][d] = Qb[off];
    Ks[wv][t][d] = Kb[off];
    vr[t] = (float)Vb[off];
  }
  __syncthreads();
  for (int idx = d; idx < TT * TT; idx += 64) {
    int tt = idx / TT, ss = idx % TT;
    float sc = 0.f;
#pragma unroll
    for (int k = 0; k < DOUT; k++)
      sc = fmaf((float)Qs[wv][tt][k], (float)Ks[wv][ss][k], sc);
    at[wv][tt][ss] = sc * 0.125f;
  }
  __syncthreads();
  if (d < TT) {
    float mx = -1e30f;
#pragma unroll
    for (int s = 0; s < TT; s++) mx = fmaxf(mx, at[wv][d][s]);
    float sum = 0.f;
#pragma unroll
    for (int s = 0; s < TT; s++) { float e = __expf(at[wv][d][s] - mx); at[wv][d][s] = e; sum += e; }
    float inv = 1.f / sum;
#pragma unroll
    for (int s = 0; s < TT; s++) at[wv][d][s] *= inv;
  }
  __syncthreads();
  float o[TT];
#pragma unroll
  for (int t = 0; t < TT; t++) o[t] = 0.f;
#pragma unroll
  for (int s = 0; s < TT; s++) {
    float vv = vr[s];
#pragma unroll
    for (int t = 0; t < TT; t++) o[t] = fmaf(at[wv][t][s], vv, o[t]);
  }
#pragma unroll
  for (int t = 0; t < TT; t++)
    out[((size_t)(b * TT + t) * NN + n) * DOUT + d] = o[t];
}

__global__ __launch_bounds__(256) void k_hlast(const float* __restrict__ h, float* __restrict__ o) {
  int i = blockIdx.x * 256 + threadIdx.x;
  if (i < BB * NN * DOUT) o[i] = h[i];
}

extern "C" void kernel_launch(void* const* d_in, const int* in_sizes, int n_in,
                              void* d_out, int out_size, void* d_ws, size_t ws_size,
                              hipStream_t stream) {
  const float* x        = (const float*)d_in[0];
  const float* init_st  = (const float*)d_in[1];
  const float* ne_tod   = (const float*)d_in[2];
  const float* ne_dow   = (const float*)d_in[3];
  const float* E        = (const float*)d_in[4];
  const float* Wtod     = (const float*)d_in[5];
  const float* btod     = (const float*)d_in[6];
  const float* Wdow     = (const float*)d_in[7];
  const float* bdow     = (const float*)d_in[8];
  const float* WQ       = (const float*)d_in[9];
  const float* bQ       = (const float*)d_in[10];
  const float* WK       = (const float*)d_in[11];
  const float* bK       = (const float*)d_in[12];
  const float* WV       = (const float*)d_in[13];
  const float* bV       = (const float*)d_in[14];
  const float* Wpool_g  = (const float*)d_in[15];
  const float* bpool_g  = (const float*)d_in[16];
  const float* Wpool_c  = (const float*)d_in[17];
  const float* bpool_c  = (const float*)d_in[18];

  float* out = (float*)d_out;
  float* hlast_out = out + (size_t)BTN * DOUT;
  // park f16 seq history in the (not-yet-written) front of d_out: 25.2 MB < 50.3 MB
  f16* seqb = (f16*)d_out;

  char* P = (char*)d_ws;
  auto alloc = [&](size_t bytes) { char* r = P; P += (bytes + 255) & ~(size_t)255; return r; };
  f16* curh  = (f16*)alloc((size_t)BB * TT * DIN * NN * 2);   // 8.26 MB
  f16* curl  = (f16*)alloc((size_t)BB * TT * DIN * NN * 2);   // 8.26 MB
  f16* Wgh   = (f16*)alloc((size_t)NN * 128 * KFP * 2);       // 46.1 MB  [n][o][k] f16 hi
  f16* Wgl   = (f16*)alloc((size_t)NN * 128 * KFP * 2);       // 46.1 MB  lo
  f16* Wch   = (f16*)alloc((size_t)NN * 64 * KFP * 2);        // 23.1 MB
  f16* Wcl   = (f16*)alloc((size_t)NN * 64 * KFP * 2);        // 23.1 MB
  float* Wp2g = (float*)alloc((size_t)128 * 22 * EMB * 8 * 4); // 901 KB transposed pool (g)
  float* Wp2c = (float*)alloc((size_t)64 * 22 * EMB * 8 * 4);  // 450 KB transposed pool (c)
  float* bg  = (float*)alloc((size_t)NN * 128 * 4);
  float* bc  = (float*)alloc((size_t)NN * 64 * 4);
  float* hb  = (float*)alloc((size_t)BB * NN * DOUT * 4);     // 4.2 MB
  f16* wbt   = (f16*)alloc((size_t)3 * DOUT * DOUT * 2);
  float* biasb = (float*)alloc(192 * 4);
  float* rb  = (float*)alloc((size_t)BB * NN * DOUT * 4);     // 4.2 MB
  float* zhb = (float*)alloc((size_t)BB * NN * DOUT * 4);     // 4.2 MB
  f16* hTh   = (f16*)alloc((size_t)BB * DOUT * NN * 2);       // 2 MB
  f16* hTl   = (f16*)alloc((size_t)BB * DOUT * NN * 2);       // 2 MB
  f16* zhTh  = (f16*)alloc((size_t)BB * DOUT * NN * 2);       // 2 MB
  f16* zhTl  = (f16*)alloc((size_t)BB * DOUT * NN * 2);       // 2 MB
  char* LOOP = P;  // loop-scoped region, overlaid by qkvb after the loop
  f16* Ah    = (f16*)alloc((size_t)BB * NN * NN * 2);         // 33.6 MB (f16, no lo)
  float* T1g = (float*)alloc((size_t)BB * NN * FP * 4);       // 6.3 MB
  float* T1c = (float*)alloc((size_t)BB * NN * DOUT * 4);     // 4.2 MB
  f16* qkvb  = (f16*)LOOP;  // 75.5 MB overlays loop region (+ free tail)
  // footprint = fixed ~178 MB + max(loop 44.1, qkvb 75.5) ≈ 253.5 MB (< 260.6 proven)

  k_embedT<<<(BB * TT * DIN * NN + 255) / 256, 256, 0, stream>>>(x, Wtod, btod, Wdow, bdow, curh, curl);
  {
    int totg = 128 * 22 * EMB * 8;
    int totc = 64 * 22 * EMB * 8;
    k_wpT<<<(totg + 255) / 256, 256, 0, stream>>>(Wpool_g, Wp2g, 128, totg);
    k_wpT<<<(totc + 255) / 256, 256, 0, stream>>>(Wpool_c, Wp2c, 64, totc);
  }
  k_poolT<<<dim3(11, 64), 256, 0, stream>>>(E, Wp2g, Wgh, Wgl, 128, 128 * 22);
  k_poolT<<<dim3(6, 64), 256, 0, stream>>>(E, Wp2c, Wch, Wcl, 64, 64 * 22);
  k_poolb<<<(NN * 128 + 255) / 256, 256, 0, stream>>>(E, bpool_g, bg, 128);
  k_poolb<<<(NN * 64 + 255) / 256, 256, 0, stream>>>(E, bpool_c, bc, 64);
  k_inith<<<(BB * NN * DOUT + 255) / 256, 256, 0, stream>>>(init_st, hb, hTh, hTl);
  k_cvtw<<<(3 * DOUT * DOUT + 192 + 255) / 256, 256, 0, stream>>>(WQ, WK, WV, bQ, bK, bV, wbt, biasb);

  // scores for t=0 (with T1 zero-fill); subsequent scores are fused into k_ncsc.
  k_scores<<<dim3(NN / 4, BB), 256, 0, stream>>>(E, ne_tod, ne_dow, 0, Ah, T1g, T1c, 1);
  for (int t = 0; t < TT; t++) {
    k_spmv_g<<<1024, 256, 0, stream>>>(Ah, curh, curl, t, hTh, hTl, T1g);
    k_nodemm_g<<<dim3(NN, 2), 256, 0, stream>>>(curh, curl, t, hb, T1g, Wgh, Wgl, bg, rb, zhb, zhTh, zhTl);
    k_spmv_c<<<1024, 256, 0, stream>>>(Ah, zhTh, zhTl, T1c);
    k_ncsc<<<NN + (NN / 4) * BB, 256, 0, stream>>>(curh, curl, t, hb, zhb, T1g, T1c,
        Wch, Wcl, bc, rb, hb, seqb, hTh, hTl, E, ne_tod, ne_dow, Ah);
  }

  k_qkv<<<BTN / 128, 256, 0, stream>>>(seqb, wbt, biasb, qkvb);
  k_attn2<<<dim3(NN / 4, BB), 256, 0, stream>>>(qkvb, out);
  k_hlast<<<(BB * NN * DOUT + 255) / 256, 256, 0, stream>>>(hb, hlast_out);
}